// Round 10
// baseline (683.675 us; speedup 1.0000x reference)
//
#include <hip/hip_runtime.h>
#include <hip/hip_bf16.h>

#define DIN 256
#define DH  1024
#define DF  512
#define NROWS 65536

// workspace layout (bytes)
#define WS_WTS   0
#define WS_PB    4718592
#define WS_PC    4980736
#define WS_CNT   5242880
#define WS_OFFS  5243904

typedef __attribute__((ext_vector_type(8))) short bf16x8;
typedef __attribute__((ext_vector_type(4))) float f32x4;

__device__ __forceinline__ unsigned short f2b(float f) {
    union { float f; unsigned u; } v; v.f = f;
    unsigned r = v.u + 0x7FFFu + ((v.u >> 16) & 1u);
    return (unsigned short)(r >> 16);
}

__device__ __forceinline__ void gll16(const void* g, void* l) {
    __builtin_amdgcn_global_load_lds(
        (const __attribute__((address_space(1))) void*)g,
        (__attribute__((address_space(3))) void*)l, 16, 0, 0);
}

// dst[n][k] = (bf16) src[k][n] ; src is K x N row-major fp32
__global__ __launch_bounds__(256) void transpose_to_bf16(
        const float* __restrict__ src, unsigned short* __restrict__ dst,
        int K, int N) {
    __shared__ float tile[64][65];
    int k0 = blockIdx.x * 64, n0 = blockIdx.y * 64;
    int t = threadIdx.x;
    for (int i = 0; i < 16; ++i) {
        int idx = t + i * 256;
        int kk = idx >> 6, nn = idx & 63;
        tile[kk][nn] = src[(size_t)(k0 + kk) * N + (n0 + nn)];
    }
    __syncthreads();
    for (int i = 0; i < 16; ++i) {
        int idx = t + i * 256;
        int nn = idx >> 6, kk = idx & 63;
        dst[(size_t)(n0 + nn) * K + (k0 + kk)] = f2b(tile[kk][nn]);
    }
}

__device__ __forceinline__ int row_tag(const float* obs, int row) {
    float c2 = obs[(size_t)row * DIN + 2];
    float c3 = obs[(size_t)row * DIN + 3];
    return (c2 == 1.0f && c3 == 0.0f) ? 1 : 0;
}

__global__ __launch_bounds__(256) void tag_count(const float* __restrict__ obs,
                                                 int* __restrict__ cnt) {
    int t = threadIdx.x;
    int tag = row_tag(obs, blockIdx.x * 256 + t);
    unsigned long long m = __ballot(tag);
    __shared__ int wc[4];
    if ((t & 63) == 0) wc[t >> 6] = __popcll(m);
    __syncthreads();
    if (t == 0) cnt[blockIdx.x] = wc[0] + wc[1] + wc[2] + wc[3];
}

__global__ __launch_bounds__(256) void scan256(const int* __restrict__ cnt,
                                               int* __restrict__ offs) {
    __shared__ int s[256];
    int t = threadIdx.x;
    s[t] = cnt[t];
    __syncthreads();
    for (int d = 1; d < 256; d <<= 1) {
        int v = (t >= d) ? s[t - d] : 0;
        __syncthreads();
        s[t] += v;
        __syncthreads();
    }
    offs[t] = s[t] - cnt[t];
    if (t == 255) offs[256] = s[255];
}

__global__ __launch_bounds__(256) void fill_perm(const float* __restrict__ obs,
                                                 const int* __restrict__ offs,
                                                 int* __restrict__ pb,
                                                 int* __restrict__ pc) {
    int t = threadIdx.x, bid = blockIdx.x;
    int row = bid * 256 + t;
    int tag = row_tag(obs, row);
    unsigned long long m = __ballot(tag);
    __shared__ int wc[4];
    int lane = t & 63, wv = t >> 6;
    if (lane == 0) wc[wv] = __popcll(m);
    __syncthreads();
    int woff = 0;
    for (int i = 0; i < 4; ++i) if (i < wv) woff += wc[i];
    int lb = woff + __popcll(m & ((1ull << lane) - 1ull));
    int base_b = offs[bid];
    if (tag) pb[base_b + lb] = row;
    else     pc[bid * 256 - base_b + (t - lb)] = row;
}

// LDS map (dynamic, 154112 B, 1 block/CU — LDS-forced, so min-waves bound of 1
// costs nothing). ALL barriers are __syncthreads (full drains, proven clean).
// R10 delta vs R9: __launch_bounds__(512, 1) — lifts the ~256-unified-reg cap
// that forced xf/hA to SPILL TO SCRATCH (the R3/R5/R7/R8/R9 hidden HBM traffic).
//   ldsX   @ 0      [128][256] bf16 = 64K  persistent, swz (r&7)<<4
//   ldsW1  @ 65536  [64][256]  bf16 = 32K  single-buffered W1 chunk
//   ldsQA  @ 98304  [128][64]  bf16 = 16K  W2 quarter ping
//   ldsQB  @ 114688 [128][64]  bf16 = 16K  W2 quarter pong
//   ldsH   @ 131072 [128][64]  bf16 = 16K
//   ldsB1  @ 147456 float[1024]
//   ldsB2  @ 151552 float[512]
//   ldsPr  @ 153600 int[128]
__global__ __launch_bounds__(512, 1) void fused_mlp(
    const float* __restrict__ obs,
    const unsigned short* __restrict__ wts,
    const int* __restrict__ perm_b, const int* __restrict__ perm_c,
    const int* __restrict__ offs,
    const float* __restrict__ b1_0, const float* __restrict__ b2_0,
    const float* __restrict__ b1_1, const float* __restrict__ b2_1,
    const float* __restrict__ b1_2, const float* __restrict__ b2_2,
    float* __restrict__ out)
{
    extern __shared__ char lds[];
    char* ldsX  = lds;
    char* ldsW1 = lds + 65536;
    char* ldsQA = lds + 98304;
    char* ldsQB = lds + 114688;
    char* ldsH  = lds + 131072;
    float* ldsB1 = (float*)(lds + 147456);
    float* ldsB2 = (float*)(lds + 151552);
    int*  ldsPr  = (int*)(lds + 153600);

    // bijective XCD swizzle: contiguous bid range per XCD
    const int ob = blockIdx.x;
    const int xcd = ob & 7, ii = ob >> 3;
    const int bid = (xcd == 0) ? ii : (129 + (xcd - 1) * 128 + ii);

    int branch, base, cnt;
    const int* perm;
    if (bid < 512) {
        branch = 2; base = bid * 128; cnt = NROWS; perm = nullptr;
    } else {
        int eb = bid - 512;
        int nb = offs[256];
        int nbb = (nb + 127) >> 7;
        int nc = NROWS - nb;
        int ncb = (nc + 127) >> 7;
        if (eb < nbb)            { branch = 0; base = eb * 128;         cnt = nb; perm = perm_b; }
        else if (eb < nbb + ncb) { branch = 1; base = (eb - nbb) * 128; cnt = nc; perm = perm_c; }
        else return;
    }

    const float* b1 = branch == 0 ? b1_0 : (branch == 1 ? b1_1 : b1_2);
    const float* b2 = branch == 0 ? b2_0 : (branch == 1 ? b2_1 : b2_2);
    const char* w1t = (const char*)(wts + (size_t)branch * (DH * DIN));
    const char* w2t = (const char*)(wts + (size_t)3 * DH * DIN + (size_t)branch * (DF * DH));

    const int t = threadIdx.x;
    const int lane = t & 63;
    const int w = t >> 6;
    const int l15 = lane & 15;
    const int g = lane >> 4;

    // ---- prologue: tables + X staging
    ldsB1[t] = b1[t];
    ldsB1[t + 512] = b1[t + 512];
    ldsB2[t] = b2[t];
    if (t < 128) {
        int gr = base + t;
        ldsPr[t] = (gr < cnt) ? (perm ? perm[gr] : gr) : -1;
    }
    #pragma unroll
    for (int i = 0; i < 16; ++i) {
        int idx = t + i * 512;
        int r = idx >> 6, c4 = idx & 63;
        int gr = base + r;
        int grow = gr < cnt ? gr : cnt - 1;
        if (perm) grow = perm[grow];
        f32x4 v = *(const f32x4*)(obs + (size_t)grow * DIN + c4 * 4);
        ushort4 p4;
        p4.x = f2b(v.x); p4.y = f2b(v.y); p4.z = f2b(v.z); p4.w = f2b(v.w);
        *(ushort4*)(ldsX + r * 512 + ((c4 * 8) ^ ((r & 7) << 4))) = p4;
    }
    // stage W1[0] (only exposed stage; once per block)
    #pragma unroll
    for (int i = 0; i < 4; ++i) {
        int slot = t + i * 512;
        int nl = slot >> 5, boff = (slot & 31) << 4;
        gll16(w1t + (size_t)nl * 512 + (boff ^ ((nl & 7) << 4)), ldsW1 + slot * 16);
    }
    __syncthreads();

    // wave roles
    const int rg = w & 3, cg = w >> 2;   // GEMM1: rows rg*32, hcols cg*32
    const int wr = w >> 2, wc = w & 3;   // GEMM2: rows wr*64, fcols wc*32/quarter

    // ---- persistent X A-frags (64 VGPR), loaded once. ldsX is read-only
    // afterwards (persistent region), so no extra barrier is required.
    bf16x8 xf[2][8];
    #pragma unroll
    for (int art = 0; art < 2; ++art)
        #pragma unroll
        for (int kk = 0; kk < 8; ++kk) {
            int ar = rg * 32 + art * 16 + l15;
            xf[art][kk] = *(const bf16x8*)(ldsX + ar * 512 + ((kk * 64 + g * 16) ^ ((ar & 7) << 4)));
        }

    const int bn0 = cg * 32 + l15, bn1 = bn0 + 16;
    const int bsw0 = (bn0 & 7) << 4, bsw1 = (bn1 & 7) << 4;

    f32x4 acc[4][8];
    #pragma unroll
    for (int a = 0; a < 4; ++a)
        #pragma unroll
        for (int b = 0; b < 8; ++b)
            #pragma unroll
            for (int e = 0; e < 4; ++e) acc[a][b][e] = 0.0f;

    // W2 quarter stage helper: quarter q of chunk hc -> buf (2 gll16/thread)
    #define STAGE_Q(buf, q, hc_)                                               \
        {                                                                      \
            _Pragma("unroll")                                                  \
            for (int i = 0; i < 2; ++i) {                                      \
                int slot = t + i * 512;                                        \
                int nl = slot >> 3, boff = (slot & 7) << 4;                    \
                gll16(w2t + (size_t)((q) * 128 + nl) * 2048 + (hc_) * 128      \
                          + (boff ^ ((nl & 7) << 4)),                          \
                      (buf) + slot * 16);                                      \
            }                                                                  \
        }

    #define QUARTER_MFMA(buf, c0)                                              \
        {                                                                      \
            _Pragma("unroll")                                                  \
            for (int k2 = 0; k2 < 2; ++k2)                                     \
                _Pragma("unroll")                                              \
                for (int ct = 0; ct < 2; ++ct) {                               \
                    int fr = wc * 32 + ct * 16 + l15;                          \
                    bf16x8 bb = *(const bf16x8*)((buf) + fr * 128 +            \
                                 ((k2 * 64 + g * 16) ^ ((fr & 7) << 4)));      \
                    _Pragma("unroll")                                          \
                    for (int rt = 0; rt < 4; ++rt)                             \
                        acc[rt][(c0) + ct] = __builtin_amdgcn_mfma_f32_16x16x32_bf16( \
                            hA[rt][k2], bb, acc[rt][(c0) + ct], 0, 0, 0);      \
                }                                                              \
        }

    for (int hc = 0; hc < 16; ++hc) {
        // ---- I1: stage q0->QA ; GEMM1 (A from xf regs) + bias/relu -> H
        STAGE_Q(ldsQA, 0, hc);
        f32x4 aH[2][2];
        #pragma unroll
        for (int a = 0; a < 2; ++a)
            #pragma unroll
            for (int b = 0; b < 2; ++b)
                #pragma unroll
                for (int e = 0; e < 4; ++e) aH[a][b][e] = 0.0f;
        __builtin_amdgcn_s_setprio(1);
        #pragma unroll
        for (int kk = 0; kk < 8; ++kk) {
            int kb = kk * 64 + g * 16;
            bf16x8 b0 = *(const bf16x8*)(ldsW1 + bn0 * 512 + (kb ^ bsw0));
            bf16x8 b1f = *(const bf16x8*)(ldsW1 + bn1 * 512 + (kb ^ bsw1));
            aH[0][0] = __builtin_amdgcn_mfma_f32_16x16x32_bf16(xf[0][kk], b0,  aH[0][0], 0, 0, 0);
            aH[0][1] = __builtin_amdgcn_mfma_f32_16x16x32_bf16(xf[0][kk], b1f, aH[0][1], 0, 0, 0);
            aH[1][0] = __builtin_amdgcn_mfma_f32_16x16x32_bf16(xf[1][kk], b0,  aH[1][0], 0, 0, 0);
            aH[1][1] = __builtin_amdgcn_mfma_f32_16x16x32_bf16(xf[1][kk], b1f, aH[1][1], 0, 0, 0);
        }
        __builtin_amdgcn_s_setprio(0);
        {
            float b1v0 = ldsB1[hc * 64 + cg * 32 + l15];
            float b1v1 = ldsB1[hc * 64 + cg * 32 + 16 + l15];
            #pragma unroll
            for (int art = 0; art < 2; ++art)
                #pragma unroll
                for (int bct = 0; bct < 2; ++bct) {
                    int col2 = (cg * 32 + bct * 16 + l15) * 2;
                    float bv = bct ? b1v1 : b1v0;
                    #pragma unroll
                    for (int r = 0; r < 4; ++r) {
                        int hrow = rg * 32 + art * 16 + g * 4 + r;
                        float vv = fmaxf(aH[art][bct][r] + bv, 0.0f);
                        *(unsigned short*)(ldsH + hrow * 128 + (col2 ^ ((hrow & 7) << 4))) = f2b(vv);
                    }
                }
        }
        __syncthreads();   // B1: drains q0; H visible

        // ---- I2: stage q1->QB ; hA loads ; GEMM2 q0 (QA)
        STAGE_Q(ldsQB, 1, hc);
        bf16x8 hA[4][2];
        #pragma unroll
        for (int rt = 0; rt < 4; ++rt)
            #pragma unroll
            for (int k2 = 0; k2 < 2; ++k2) {
                int hr = wr * 64 + rt * 16 + l15;
                hA[rt][k2] = *(const bf16x8*)(ldsH + hr * 128 + ((k2 * 64 + g * 16) ^ ((hr & 7) << 4)));
            }
        __builtin_amdgcn_s_setprio(1);
        QUARTER_MFMA(ldsQA, 0);
        __builtin_amdgcn_s_setprio(0);
        __syncthreads();   // B2: drains q1

        // ---- I3: stage q2->QA ; GEMM2 q1 (QB)
        STAGE_Q(ldsQA, 2, hc);
        __builtin_amdgcn_s_setprio(1);
        QUARTER_MFMA(ldsQB, 2);
        __builtin_amdgcn_s_setprio(0);
        __syncthreads();   // B3: drains q2

        // ---- I4: stage q3->QB ; GEMM2 q2 (QA)
        STAGE_Q(ldsQB, 3, hc);
        __builtin_amdgcn_s_setprio(1);
        QUARTER_MFMA(ldsQA, 4);
        __builtin_amdgcn_s_setprio(0);
        __syncthreads();   // B4: drains q3

        // ---- I5: stage W1[hc+1] ; GEMM2 q3 (QB)
        if (hc < 15) {
            int nchunk = hc + 1;
            #pragma unroll
            for (int i = 0; i < 4; ++i) {
                int slot = t + i * 512;
                int nl = slot >> 5, boff = (slot & 31) << 4;
                gll16(w1t + (size_t)(nchunk * 64 + nl) * 512 + (boff ^ ((nl & 7) << 4)),
                      ldsW1 + slot * 16);
            }
        }
        __builtin_amdgcn_s_setprio(1);
        QUARTER_MFMA(ldsQB, 6);
        __builtin_amdgcn_s_setprio(0);
        __syncthreads();   // B5: drains W1[hc+1]
    }

    // ---- epilogue: bias2 + permuted scatter store
    int colq[8]; float b2v[8];
    #pragma unroll
    for (int q = 0; q < 8; ++q) {
        colq[q] = (q >> 1) * 128 + wc * 32 + (q & 1) * 16 + l15;
        b2v[q] = ldsB2[colq[q]];
    }
    const int cb = (branch == 2) ? DF : 0;
    #pragma unroll
    for (int rt = 0; rt < 4; ++rt)
        #pragma unroll
        for (int r = 0; r < 4; ++r) {
            int row = wr * 64 + rt * 16 + g * 4 + r;
            int prow = ldsPr[row];
            if (prow >= 0) {
                float* op = out + (size_t)prow * (2 * DF) + cb;
                #pragma unroll
                for (int q = 0; q < 8; ++q)
                    op[colq[q]] = acc[rt][q][r] + b2v[q];
            }
        }
}

extern "C" void kernel_launch(void* const* d_in, const int* in_sizes, int n_in,
                              void* d_out, int out_size, void* d_ws, size_t ws_size,
                              hipStream_t stream) {
    const float* obs = (const float*)d_in[0];
    const float* W1[3] = {(const float*)d_in[1], (const float*)d_in[5], (const float*)d_in[9]};
    const float* b1[3] = {(const float*)d_in[2], (const float*)d_in[6], (const float*)d_in[10]};
    const float* W2[3] = {(const float*)d_in[3], (const float*)d_in[7], (const float*)d_in[11]};
    const float* b2[3] = {(const float*)d_in[4], (const float*)d_in[8], (const float*)d_in[12]};

    char* ws = (char*)d_ws;
    unsigned short* wts = (unsigned short*)(ws + WS_WTS);
    int* pb   = (int*)(ws + WS_PB);
    int* pc   = (int*)(ws + WS_PC);
    int* cnt  = (int*)(ws + WS_CNT);
    int* offs = (int*)(ws + WS_OFFS);

    for (int br = 0; br < 3; ++br) {
        transpose_to_bf16<<<dim3(DIN / 64, DH / 64), 256, 0, stream>>>(
            W1[br], wts + (size_t)br * DH * DIN, DIN, DH);
        transpose_to_bf16<<<dim3(DH / 64, DF / 64), 256, 0, stream>>>(
            W2[br], wts + (size_t)3 * DH * DIN + (size_t)br * DF * DH, DH, DF);
    }
    tag_count<<<256, 256, 0, stream>>>(obs, cnt);
    scan256<<<1, 256, 0, stream>>>(cnt, offs);
    fill_perm<<<256, 256, 0, stream>>>(obs, offs, pb, pc);

    hipFuncSetAttribute((const void*)fused_mlp,
                        hipFuncAttributeMaxDynamicSharedMemorySize, 154112);
    fused_mlp<<<1025, 512, 154112, stream>>>(obs, wts, pb, pc, offs,
        b1[0], b2[0], b1[1], b2[1], b1[2], b2[2], (float*)d_out);
}

// Round 11
// 450.094 us; speedup vs baseline: 1.5190x; 1.5190x over previous
//
#include <hip/hip_runtime.h>
#include <hip/hip_bf16.h>

#define DIN 256
#define DH  1024
#define DF  512
#define NROWS 65536

// workspace layout (bytes)
#define WS_WTS   0
#define WS_PB    4718592
#define WS_PC    4980736
#define WS_CNT   5242880
#define WS_OFFS  5243904
#define WS_U     5248000
#define WS_H     8388608ull
#define WS_NEED  (8388608ull + 134742016ull)   // H worst case: 65792 rows x 1024 bf16

typedef __attribute__((ext_vector_type(8))) short bf16x8;
typedef __attribute__((ext_vector_type(4))) float f32x4;

__device__ __forceinline__ unsigned short f2b(float f) {
    union { float f; unsigned u; } v; v.f = f;
    unsigned r = v.u + 0x7FFFu + ((v.u >> 16) & 1u);
    return (unsigned short)(r >> 16);
}

__device__ __forceinline__ void gll16(const void* g, void* l) {
    __builtin_amdgcn_global_load_lds(
        (const __attribute__((address_space(1))) void*)g,
        (__attribute__((address_space(3))) void*)l, 16, 0, 0);
}

// dst[n][k] = (bf16) src[k][n] ; src is K x N row-major fp32
__global__ __launch_bounds__(256) void transpose_to_bf16(
        const float* __restrict__ src, unsigned short* __restrict__ dst,
        int K, int N) {
    __shared__ float tile[64][65];
    int k0 = blockIdx.x * 64, n0 = blockIdx.y * 64;
    int t = threadIdx.x;
    for (int i = 0; i < 16; ++i) {
        int idx = t + i * 256;
        int kk = idx >> 6, nn = idx & 63;
        tile[kk][nn] = src[(size_t)(k0 + kk) * N + (n0 + nn)];
    }
    __syncthreads();
    for (int i = 0; i < 16; ++i) {
        int idx = t + i * 256;
        int nn = idx >> 6, kk = idx & 63;
        dst[(size_t)(n0 + nn) * K + (k0 + kk)] = f2b(tile[kk][nn]);
    }
}

__device__ __forceinline__ int row_tag(const float* obs, int row) {
    float c2 = obs[(size_t)row * DIN + 2];
    float c3 = obs[(size_t)row * DIN + 3];
    return (c2 == 1.0f && c3 == 0.0f) ? 1 : 0;
}

__global__ __launch_bounds__(256) void tag_count(const float* __restrict__ obs,
                                                 int* __restrict__ cnt) {
    int t = threadIdx.x;
    int tag = row_tag(obs, blockIdx.x * 256 + t);
    unsigned long long m = __ballot(tag);
    __shared__ int wc[4];
    if ((t & 63) == 0) wc[t >> 6] = __popcll(m);
    __syncthreads();
    if (t == 0) cnt[blockIdx.x] = wc[0] + wc[1] + wc[2] + wc[3];
}

__global__ __launch_bounds__(256) void scan256(const int* __restrict__ cnt,
                                               int* __restrict__ offs) {
    __shared__ int s[256];
    int t = threadIdx.x;
    s[t] = cnt[t];
    __syncthreads();
    for (int d = 1; d < 256; d <<= 1) {
        int v = (t >= d) ? s[t - d] : 0;
        __syncthreads();
        s[t] += v;
        __syncthreads();
    }
    offs[t] = s[t] - cnt[t];
    if (t == 255) offs[256] = s[255];
}

// split perms for the fused fallback
__global__ __launch_bounds__(256) void fill_perm(const float* __restrict__ obs,
                                                 const int* __restrict__ offs,
                                                 int* __restrict__ pb,
                                                 int* __restrict__ pc) {
    int t = threadIdx.x, bid = blockIdx.x;
    int row = bid * 256 + t;
    int tag = row_tag(obs, row);
    unsigned long long m = __ballot(tag);
    __shared__ int wc[4];
    int lane = t & 63, wv = t >> 6;
    if (lane == 0) wc[wv] = __popcll(m);
    __syncthreads();
    int woff = 0;
    for (int i = 0; i < 4; ++i) if (i < wv) woff += wc[i];
    int lb = woff + __popcll(m & ((1ull << lane) - 1ull));
    int base_b = offs[bid];
    if (tag) pb[base_b + lb] = row;
    else     pc[bid * 256 - base_b + (t - lb)] = row;
}

// unified perm for the split path: U = [tag==1 rows (b)] ++ [tag==0 rows (c)]
__global__ __launch_bounds__(256) void fill_permU(const float* __restrict__ obs,
                                                  const int* __restrict__ offs,
                                                  int* __restrict__ U) {
    int t = threadIdx.x, bid = blockIdx.x;
    int row = bid * 256 + t;
    int tag = row_tag(obs, row);
    unsigned long long m = __ballot(tag);
    __shared__ int wc[4];
    int lane = t & 63, wv = t >> 6;
    if (lane == 0) wc[wv] = __popcll(m);
    __syncthreads();
    int woff = 0;
    for (int i = 0; i < 4; ++i) if (i < wv) woff += wc[i];
    int lb = woff + __popcll(m & ((1ull << lane) - 1ull));
    int base_b = offs[bid];
    int nb = offs[256];
    if (tag) U[base_b + lb] = row;
    else     U[nb + bid * 256 - base_b + (t - lb)] = row;
}

// ============================ split path ============================
// K1: H[ev][0..1024) = relu(X[row(ev)] . W1_br + b1_br), bf16.
// mode 0: ev = natural row, branch p. mode 1: ev indexes padded U-list
// (b-section padded to 128-mult with duplicates of U[nb-1], then c).
// LDS: X 64K @0 (swz), W1a 32K @65536, W1b 32K @98304, B1 4K @131072 = 135168.
__global__ __launch_bounds__(512, 1) void k1_hidden(
    const float* __restrict__ obs, const unsigned short* __restrict__ wts,
    const int* __restrict__ U, const int* __restrict__ offs,
    const float* __restrict__ b1_0, const float* __restrict__ b1_1,
    const float* __restrict__ b1_2,
    unsigned short* __restrict__ H, int mode)
{
    extern __shared__ char lds[];
    char* ldsX   = lds;
    char* ldsW1a = lds + 65536;
    char* ldsW1b = lds + 98304;
    float* ldsB1 = (float*)(lds + 131072);

    const int bid = blockIdx.x;
    const int nb  = offs[256];
    const int nc  = NROWS - nb;
    const int nbp = (nb + 127) & ~127;
    const int ncp = (nc + 127) & ~127;
    const int evb = bid * 128;
    int branch;
    if (mode == 0) branch = 2;
    else {
        if (evb >= nbp + ncp) return;
        branch = (evb < nbp) ? 0 : 1;
    }
    const float* b1g = branch == 0 ? b1_0 : (branch == 1 ? b1_1 : b1_2);
    const char* w1t = (const char*)(wts + (size_t)branch * (DH * DIN));

    const int t = threadIdx.x;
    const int lane = t & 63;
    const int w = t >> 6;
    const int l15 = lane & 15;
    const int g = lane >> 4;

    ldsB1[t] = b1g[t];
    ldsB1[t + 512] = b1g[t + 512];

    // stage X (fp32->bf16, swizzled)
    #pragma unroll
    for (int i = 0; i < 16; ++i) {
        int idx = t + i * 512;
        int r = idx >> 6, c4 = idx & 63;
        int j = evb + r;
        int grow;
        if (mode == 0) grow = j;
        else if (j < nbp) grow = U[j < nb ? j : nb - 1];
        else { int ix = j - nbp; grow = U[nb + (ix < nc ? ix : nc - 1)]; }
        f32x4 v = *(const f32x4*)(obs + (size_t)grow * DIN + c4 * 4);
        ushort4 p4;
        p4.x = f2b(v.x); p4.y = f2b(v.y); p4.z = f2b(v.z); p4.w = f2b(v.w);
        *(ushort4*)(ldsX + r * 512 + ((c4 * 8) ^ ((r & 7) << 4))) = p4;
    }
    // stage W1 chunk 0
    #pragma unroll
    for (int i = 0; i < 4; ++i) {
        int slot = t + i * 512;
        int nl = slot >> 5, boff = (slot & 31) << 4;
        gll16(w1t + (size_t)nl * 512 + (boff ^ ((nl & 7) << 4)), ldsW1a + slot * 16);
    }
    __syncthreads();

    const int rg = w & 3, cg = w >> 2;
    const int ar0 = rg * 32 + l15, ar1 = ar0 + 16;
    const int asw0 = (ar0 & 7) << 4, asw1 = (ar1 & 7) << 4;
    const int bn0 = cg * 32 + l15, bn1 = bn0 + 16;
    const int bsw0 = (bn0 & 7) << 4, bsw1 = (bn1 & 7) << 4;
    const size_t hb = (size_t)bid * 128;

    for (int wch = 0; wch < 16; ++wch) {
        const char* Wc = (wch & 1) ? ldsW1b : ldsW1a;
        if (wch < 15) {
            char* dst = (wch & 1) ? ldsW1a : ldsW1b;
            #pragma unroll
            for (int i = 0; i < 4; ++i) {
                int slot = t + i * 512;
                int nl = slot >> 5, boff = (slot & 31) << 4;
                gll16(w1t + (size_t)((wch + 1) * 64 + nl) * 512 + (boff ^ ((nl & 7) << 4)),
                      dst + slot * 16);
            }
        }
        f32x4 aH[2][2];
        #pragma unroll
        for (int a = 0; a < 2; ++a)
            #pragma unroll
            for (int b = 0; b < 2; ++b)
                #pragma unroll
                for (int e = 0; e < 4; ++e) aH[a][b][e] = 0.0f;
        __builtin_amdgcn_s_setprio(1);
        #pragma unroll
        for (int kk = 0; kk < 8; ++kk) {
            int kb = kk * 64 + g * 16;
            bf16x8 a0  = *(const bf16x8*)(ldsX + ar0 * 512 + (kb ^ asw0));
            bf16x8 a1  = *(const bf16x8*)(ldsX + ar1 * 512 + (kb ^ asw1));
            bf16x8 b0  = *(const bf16x8*)(Wc + bn0 * 512 + (kb ^ bsw0));
            bf16x8 b1f = *(const bf16x8*)(Wc + bn1 * 512 + (kb ^ bsw1));
            aH[0][0] = __builtin_amdgcn_mfma_f32_16x16x32_bf16(a0, b0,  aH[0][0], 0, 0, 0);
            aH[0][1] = __builtin_amdgcn_mfma_f32_16x16x32_bf16(a0, b1f, aH[0][1], 0, 0, 0);
            aH[1][0] = __builtin_amdgcn_mfma_f32_16x16x32_bf16(a1, b0,  aH[1][0], 0, 0, 0);
            aH[1][1] = __builtin_amdgcn_mfma_f32_16x16x32_bf16(a1, b1f, aH[1][1], 0, 0, 0);
        }
        __builtin_amdgcn_s_setprio(0);
        {
            float b1v0 = ldsB1[wch * 64 + cg * 32 + l15];
            float b1v1 = ldsB1[wch * 64 + cg * 32 + 16 + l15];
            #pragma unroll
            for (int art = 0; art < 2; ++art)
                #pragma unroll
                for (int bct = 0; bct < 2; ++bct) {
                    float bv = bct ? b1v1 : b1v0;
                    int hcol = wch * 64 + cg * 32 + bct * 16 + l15;
                    #pragma unroll
                    for (int r = 0; r < 4; ++r) {
                        int hrow = rg * 32 + art * 16 + g * 4 + r;
                        float vv = fmaxf(aH[art][bct][r] + bv, 0.0f);
                        H[(hb + hrow) * DH + hcol] = f2b(vv);
                    }
                }
        }
        __syncthreads();
    }
}

// K2: out-tile = H-tile . W2_br + b2, 128 evals x 512 cols, K=1024 in 16 chunks.
// LDS: HA 16K @0, HB 16K @16384, W2A 32K @32768, W2B 32K @65536,
//      B2 2K @98304, Pr 512B @100352 = 100864.
__global__ __launch_bounds__(512, 1) void k2_out(
    const unsigned short* __restrict__ H, const unsigned short* __restrict__ wts,
    const int* __restrict__ U, const int* __restrict__ offs,
    const float* __restrict__ b2_0, const float* __restrict__ b2_1,
    const float* __restrict__ b2_2,
    float* __restrict__ out, int mode)
{
    extern __shared__ char lds[];
    char* ldsHA  = lds;
    char* ldsHB  = lds + 16384;
    char* ldsW2A = lds + 32768;
    char* ldsW2B = lds + 65536;
    float* ldsB2 = (float*)(lds + 98304);
    int*  ldsPr  = (int*)(lds + 100352);

    const int bid = blockIdx.x;
    const int nb  = offs[256];
    const int nc  = NROWS - nb;
    const int nbp = (nb + 127) & ~127;
    const int ncp = (nc + 127) & ~127;
    const int evb = bid * 128;
    int branch;
    if (mode == 0) branch = 2;
    else {
        if (evb >= nbp + ncp) return;
        branch = (evb < nbp) ? 0 : 1;
    }
    const float* b2g = branch == 0 ? b2_0 : (branch == 1 ? b2_1 : b2_2);
    const char* w2t = (const char*)(wts + (size_t)3 * DH * DIN + (size_t)branch * (DF * DH));

    const int t = threadIdx.x;
    const int lane = t & 63;
    const int w = t >> 6;
    const int l15 = lane & 15;
    const int g = lane >> 4;

    ldsB2[t] = b2g[t];
    if (t < 128) {
        int j = evb + t;
        int pr;
        if (mode == 0) pr = j;
        else if (j < nbp) pr = U[j < nb ? j : nb - 1];
        else { int ix = j - nbp; pr = U[nb + (ix < nc ? ix : nc - 1)]; }
        ldsPr[t] = pr;
    }
    const size_t hb = (size_t)bid * 128;

    // stage H chunk0 -> HA ; W2 half0 chunk0 -> W2A
    #pragma unroll
    for (int i = 0; i < 2; ++i) {
        int slot = t + i * 512;
        int nl = slot >> 3, boff = (slot & 7) << 4;
        gll16((const char*)H + (hb + nl) * 2048 + (boff ^ ((nl & 7) << 4)),
              ldsHA + slot * 16);
    }
    #pragma unroll
    for (int i = 0; i < 4; ++i) {
        int slot = t + i * 512;
        int nl = slot >> 3, boff = (slot & 7) << 4;
        gll16(w2t + (size_t)nl * 2048 + (boff ^ ((nl & 7) << 4)), ldsW2A + slot * 16);
    }
    __syncthreads();

    const int wr = w >> 2, wc = w & 3;
    f32x4 acc[4][8];
    #pragma unroll
    for (int a = 0; a < 4; ++a)
        #pragma unroll
        for (int b = 0; b < 8; ++b)
            #pragma unroll
            for (int e = 0; e < 4; ++e) acc[a][b][e] = 0.0f;

    for (int ch = 0; ch < 16; ++ch) {
        const char* Hc = (ch & 1) ? ldsHB : ldsHA;
        // I1: stage W2 half1(ch); hA loads; MFMA half0 (W2A)
        #pragma unroll
        for (int i = 0; i < 4; ++i) {
            int slot = t + i * 512;
            int nl = slot >> 3, boff = (slot & 7) << 4;
            gll16(w2t + (size_t)(256 + nl) * 2048 + ch * 128 + (boff ^ ((nl & 7) << 4)),
                  ldsW2B + slot * 16);
        }
        bf16x8 hA[4][2];
        #pragma unroll
        for (int rt = 0; rt < 4; ++rt)
            #pragma unroll
            for (int k2 = 0; k2 < 2; ++k2) {
                int hr = wr * 64 + rt * 16 + l15;
                hA[rt][k2] = *(const bf16x8*)(Hc + hr * 128 + ((k2 * 64 + g * 16) ^ ((hr & 7) << 4)));
            }
        __builtin_amdgcn_s_setprio(1);
        #pragma unroll
        for (int k2 = 0; k2 < 2; ++k2)
            #pragma unroll
            for (int ct = 0; ct < 4; ++ct) {
                int fr = wc * 64 + ct * 16 + l15;
                bf16x8 bb = *(const bf16x8*)(ldsW2A + fr * 128 + ((k2 * 64 + g * 16) ^ ((fr & 7) << 4)));
                #pragma unroll
                for (int rt = 0; rt < 4; ++rt)
                    acc[rt][ct] = __builtin_amdgcn_mfma_f32_16x16x32_bf16(hA[rt][k2], bb, acc[rt][ct], 0, 0, 0);
            }
        __builtin_amdgcn_s_setprio(0);
        __syncthreads();

        // I2: stage H(ch+1) + W2 half0(ch+1); MFMA half1 (W2B)
        if (ch < 15) {
            char* hd = (ch & 1) ? ldsHA : ldsHB;
            #pragma unroll
            for (int i = 0; i < 2; ++i) {
                int slot = t + i * 512;
                int nl = slot >> 3, boff = (slot & 7) << 4;
                gll16((const char*)H + (hb + nl) * 2048 + (ch + 1) * 128 + (boff ^ ((nl & 7) << 4)),
                      hd + slot * 16);
            }
            #pragma unroll
            for (int i = 0; i < 4; ++i) {
                int slot = t + i * 512;
                int nl = slot >> 3, boff = (slot & 7) << 4;
                gll16(w2t + (size_t)nl * 2048 + (ch + 1) * 128 + (boff ^ ((nl & 7) << 4)),
                      ldsW2A + slot * 16);
            }
        }
        __builtin_amdgcn_s_setprio(1);
        #pragma unroll
        for (int k2 = 0; k2 < 2; ++k2)
            #pragma unroll
            for (int ct = 0; ct < 4; ++ct) {
                int fr = wc * 64 + ct * 16 + l15;
                bf16x8 bb = *(const bf16x8*)(ldsW2B + fr * 128 + ((k2 * 64 + g * 16) ^ ((fr & 7) << 4)));
                #pragma unroll
                for (int rt = 0; rt < 4; ++rt)
                    acc[rt][4 + ct] = __builtin_amdgcn_mfma_f32_16x16x32_bf16(hA[rt][k2], bb, acc[rt][4 + ct], 0, 0, 0);
            }
        __builtin_amdgcn_s_setprio(0);
        __syncthreads();
    }

    // epilogue
    const int colbase = (mode == 0) ? DF : 0;
    int colq[8]; float b2v[8];
    #pragma unroll
    for (int q = 0; q < 8; ++q) {
        colq[q] = (q >> 2) * 256 + wc * 64 + (q & 3) * 16 + l15;
        b2v[q] = ldsB2[colq[q]];
    }
    #pragma unroll
    for (int rt = 0; rt < 4; ++rt)
        #pragma unroll
        for (int r = 0; r < 4; ++r) {
            int row = wr * 64 + rt * 16 + g * 4 + r;
            int prow = ldsPr[row];
            float* op = out + (size_t)prow * (2 * DF) + colbase;
            #pragma unroll
            for (int q = 0; q < 8; ++q)
                op[colq[q]] = acc[rt][q][r] + b2v[q];
        }
}

// ======================= fused fallback (R6, 376 us proven) =======================
__global__ __launch_bounds__(512, 2) void fused_mlp(
    const float* __restrict__ obs,
    const unsigned short* __restrict__ wts,
    const int* __restrict__ perm_b, const int* __restrict__ perm_c,
    const int* __restrict__ offs,
    const float* __restrict__ b1_0, const float* __restrict__ b2_0,
    const float* __restrict__ b1_1, const float* __restrict__ b2_1,
    const float* __restrict__ b1_2, const float* __restrict__ b2_2,
    float* __restrict__ out)
{
    extern __shared__ char lds[];
    char* ldsX  = lds;
    char* ldsW1 = lds + 65536;
    char* ldsQA = lds + 98304;
    char* ldsQB = lds + 114688;
    char* ldsH  = lds + 131072;
    float* ldsB1 = (float*)(lds + 147456);
    float* ldsB2 = (float*)(lds + 151552);
    int*  ldsPr  = (int*)(lds + 153600);

    const int ob = blockIdx.x;
    const int xcd = ob & 7, ii = ob >> 3;
    const int bid = (xcd == 0) ? ii : (129 + (xcd - 1) * 128 + ii);

    int branch, base, cnt;
    const int* perm;
    if (bid < 512) {
        branch = 2; base = bid * 128; cnt = NROWS; perm = nullptr;
    } else {
        int eb = bid - 512;
        int nb = offs[256];
        int nbb = (nb + 127) >> 7;
        int nc = NROWS - nb;
        int ncb = (nc + 127) >> 7;
        if (eb < nbb)            { branch = 0; base = eb * 128;         cnt = nb; perm = perm_b; }
        else if (eb < nbb + ncb) { branch = 1; base = (eb - nbb) * 128; cnt = nc; perm = perm_c; }
        else return;
    }

    const float* b1 = branch == 0 ? b1_0 : (branch == 1 ? b1_1 : b1_2);
    const float* b2 = branch == 0 ? b2_0 : (branch == 1 ? b2_1 : b2_2);
    const char* w1t = (const char*)(wts + (size_t)branch * (DH * DIN));
    const char* w2t = (const char*)(wts + (size_t)3 * DH * DIN + (size_t)branch * (DF * DH));

    const int t = threadIdx.x;
    const int lane = t & 63;
    const int w = t >> 6;
    const int l15 = lane & 15;
    const int g = lane >> 4;

    ldsB1[t] = b1[t];
    ldsB1[t + 512] = b1[t + 512];
    ldsB2[t] = b2[t];
    if (t < 128) {
        int gr = base + t;
        ldsPr[t] = (gr < cnt) ? (perm ? perm[gr] : gr) : -1;
    }
    #pragma unroll
    for (int i = 0; i < 16; ++i) {
        int idx = t + i * 512;
        int r = idx >> 6, c4 = idx & 63;
        int gr = base + r;
        int grow = gr < cnt ? gr : cnt - 1;
        if (perm) grow = perm[grow];
        f32x4 v = *(const f32x4*)(obs + (size_t)grow * DIN + c4 * 4);
        ushort4 p4;
        p4.x = f2b(v.x); p4.y = f2b(v.y); p4.z = f2b(v.z); p4.w = f2b(v.w);
        *(ushort4*)(ldsX + r * 512 + ((c4 * 8) ^ ((r & 7) << 4))) = p4;
    }
    #pragma unroll
    for (int i = 0; i < 4; ++i) {
        int slot = t + i * 512;
        int nl = slot >> 5, boff = (slot & 31) << 4;
        gll16(w1t + (size_t)nl * 512 + (boff ^ ((nl & 7) << 4)), ldsW1 + slot * 16);
    }
    __syncthreads();

    const int rg = w & 3, cg = w >> 2;
    const int wr = w >> 2, wc = w & 3;

    const int ar0 = rg * 32 + l15, ar1 = ar0 + 16;
    const int asw0 = (ar0 & 7) << 4, asw1 = (ar1 & 7) << 4;
    const int bn0 = cg * 32 + l15, bn1 = bn0 + 16;
    const int bsw0 = (bn0 & 7) << 4, bsw1 = (bn1 & 7) << 4;

    f32x4 acc[4][8];
    #pragma unroll
    for (int a = 0; a < 4; ++a)
        #pragma unroll
        for (int b = 0; b < 8; ++b)
            #pragma unroll
            for (int e = 0; e < 4; ++e) acc[a][b][e] = 0.0f;

    #define STAGE_Q(buf, q, hc_)                                               \
        {                                                                      \
            _Pragma("unroll")                                                  \
            for (int i = 0; i < 2; ++i) {                                      \
                int slot = t + i * 512;                                        \
                int nl = slot >> 3, boff = (slot & 7) << 4;                    \
                gll16(w2t + (size_t)((q) * 128 + nl) * 2048 + (hc_) * 128      \
                          + (boff ^ ((nl & 7) << 4)),                          \
                      (buf) + slot * 16);                                      \
            }                                                                  \
        }

    #define QUARTER_MFMA(buf, c0)                                              \
        {                                                                      \
            _Pragma("unroll")                                                  \
            for (int k2 = 0; k2 < 2; ++k2)                                     \
                _Pragma("unroll")                                              \
                for (int ct = 0; ct < 2; ++ct) {                               \
                    int fr = wc * 32 + ct * 16 + l15;                          \
                    bf16x8 bb = *(const bf16x8*)((buf) + fr * 128 +            \
                                 ((k2 * 64 + g * 16) ^ ((fr & 7) << 4)));      \
                    _Pragma("unroll")                                          \
                    for (int rt = 0; rt < 4; ++rt)                             \
                        acc[rt][(c0) + ct] = __builtin_amdgcn_mfma_f32_16x16x32_bf16( \
                            hA[rt][k2], bb, acc[rt][(c0) + ct], 0, 0, 0);      \
                }                                                              \
        }

    for (int hc = 0; hc < 16; ++hc) {
        STAGE_Q(ldsQA, 0, hc);
        f32x4 aH[2][2];
        #pragma unroll
        for (int a = 0; a < 2; ++a)
            #pragma unroll
            for (int b = 0; b < 2; ++b)
                #pragma unroll
                for (int e = 0; e < 4; ++e) aH[a][b][e] = 0.0f;
        __builtin_amdgcn_s_setprio(1);
        #pragma unroll
        for (int kk = 0; kk < 8; ++kk) {
            int kb = kk * 64 + g * 16;
            bf16x8 a0 = *(const bf16x8*)(ldsX  + ar0 * 512 + (kb ^ asw0));
            bf16x8 a1 = *(const bf16x8*)(ldsX  + ar1 * 512 + (kb ^ asw1));
            bf16x8 b0 = *(const bf16x8*)(ldsW1 + bn0 * 512 + (kb ^ bsw0));
            bf16x8 b1f = *(const bf16x8*)(ldsW1 + bn1 * 512 + (kb ^ bsw1));
            aH[0][0] = __builtin_amdgcn_mfma_f32_16x16x32_bf16(a0, b0,  aH[0][0], 0, 0, 0);
            aH[0][1] = __builtin_amdgcn_mfma_f32_16x16x32_bf16(a0, b1f, aH[0][1], 0, 0, 0);
            aH[1][0] = __builtin_amdgcn_mfma_f32_16x16x32_bf16(a1, b0,  aH[1][0], 0, 0, 0);
            aH[1][1] = __builtin_amdgcn_mfma_f32_16x16x32_bf16(a1, b1f, aH[1][1], 0, 0, 0);
        }
        __builtin_amdgcn_s_setprio(0);
        {
            float b1v0 = ldsB1[hc * 64 + cg * 32 + l15];
            float b1v1 = ldsB1[hc * 64 + cg * 32 + 16 + l15];
            #pragma unroll
            for (int art = 0; art < 2; ++art)
                #pragma unroll
                for (int bct = 0; bct < 2; ++bct) {
                    int col2 = (cg * 32 + bct * 16 + l15) * 2;
                    float bv = bct ? b1v1 : b1v0;
                    #pragma unroll
                    for (int r = 0; r < 4; ++r) {
                        int hrow = rg * 32 + art * 16 + g * 4 + r;
                        float vv = fmaxf(aH[art][bct][r] + bv, 0.0f);
                        *(unsigned short*)(ldsH + hrow * 128 + (col2 ^ ((hrow & 7) << 4))) = f2b(vv);
                    }
                }
        }
        __syncthreads();

        STAGE_Q(ldsQB, 1, hc);
        bf16x8 hA[4][2];
        #pragma unroll
        for (int rt = 0; rt < 4; ++rt)
            #pragma unroll
            for (int k2 = 0; k2 < 2; ++k2) {
                int hr = wr * 64 + rt * 16 + l15;
                hA[rt][k2] = *(const bf16x8*)(ldsH + hr * 128 + ((k2 * 64 + g * 16) ^ ((hr & 7) << 4)));
            }
        __builtin_amdgcn_s_setprio(1);
        QUARTER_MFMA(ldsQA, 0);
        __builtin_amdgcn_s_setprio(0);
        __syncthreads();

        STAGE_Q(ldsQA, 2, hc);
        __builtin_amdgcn_s_setprio(1);
        QUARTER_MFMA(ldsQB, 2);
        __builtin_amdgcn_s_setprio(0);
        __syncthreads();

        STAGE_Q(ldsQB, 3, hc);
        __builtin_amdgcn_s_setprio(1);
        QUARTER_MFMA(ldsQA, 4);
        __builtin_amdgcn_s_setprio(0);
        __syncthreads();

        if (hc < 15) {
            int nchunk = hc + 1;
            #pragma unroll
            for (int i = 0; i < 4; ++i) {
                int slot = t + i * 512;
                int nl = slot >> 5, boff = (slot & 31) << 4;
                gll16(w1t + (size_t)(nchunk * 64 + nl) * 512 + (boff ^ ((nl & 7) << 4)),
                      ldsW1 + slot * 16);
            }
        }
        __builtin_amdgcn_s_setprio(1);
        QUARTER_MFMA(ldsQB, 6);
        __builtin_amdgcn_s_setprio(0);
        __syncthreads();
    }

    int colq[8]; float b2v[8];
    #pragma unroll
    for (int q = 0; q < 8; ++q) {
        colq[q] = (q >> 1) * 128 + wc * 32 + (q & 1) * 16 + l15;
        b2v[q] = ldsB2[colq[q]];
    }
    const int cb = (branch == 2) ? DF : 0;
    #pragma unroll
    for (int rt = 0; rt < 4; ++rt)
        #pragma unroll
        for (int r = 0; r < 4; ++r) {
            int row = wr * 64 + rt * 16 + g * 4 + r;
            int prow = ldsPr[row];
            if (prow >= 0) {
                float* op = out + (size_t)prow * (2 * DF) + cb;
                #pragma unroll
                for (int q = 0; q < 8; ++q)
                    op[colq[q]] = acc[rt][q][r] + b2v[q];
            }
        }
}

extern "C" void kernel_launch(void* const* d_in, const int* in_sizes, int n_in,
                              void* d_out, int out_size, void* d_ws, size_t ws_size,
                              hipStream_t stream) {
    const float* obs = (const float*)d_in[0];
    const float* W1[3] = {(const float*)d_in[1], (const float*)d_in[5], (const float*)d_in[9]};
    const float* b1[3] = {(const float*)d_in[2], (const float*)d_in[6], (const float*)d_in[10]};
    const float* W2[3] = {(const float*)d_in[3], (const float*)d_in[7], (const float*)d_in[11]};
    const float* b2[3] = {(const float*)d_in[4], (const float*)d_in[8], (const float*)d_in[12]};

    char* ws = (char*)d_ws;
    unsigned short* wts = (unsigned short*)(ws + WS_WTS);
    int* pb   = (int*)(ws + WS_PB);
    int* pc   = (int*)(ws + WS_PC);
    int* cnt  = (int*)(ws + WS_CNT);
    int* offs = (int*)(ws + WS_OFFS);
    int* U    = (int*)(ws + WS_U);
    unsigned short* Hws = (unsigned short*)(ws + WS_H);

    for (int br = 0; br < 3; ++br) {
        transpose_to_bf16<<<dim3(DIN / 64, DH / 64), 256, 0, stream>>>(
            W1[br], wts + (size_t)br * DH * DIN, DIN, DH);
        transpose_to_bf16<<<dim3(DH / 64, DF / 64), 256, 0, stream>>>(
            W2[br], wts + (size_t)3 * DH * DIN + (size_t)br * DF * DH, DH, DF);
    }
    tag_count<<<256, 256, 0, stream>>>(obs, cnt);
    scan256<<<1, 256, 0, stream>>>(cnt, offs);

    if (ws_size >= WS_NEED) {
        fill_permU<<<256, 256, 0, stream>>>(obs, offs, U);
        hipFuncSetAttribute((const void*)k1_hidden,
                            hipFuncAttributeMaxDynamicSharedMemorySize, 135168);
        hipFuncSetAttribute((const void*)k2_out,
                            hipFuncAttributeMaxDynamicSharedMemorySize, 100864);
        // phase p (mode 0): 512 row-tiles
        k1_hidden<<<512, 512, 135168, stream>>>(obs, wts, U, offs,
            b1[0], b1[1], b1[2], Hws, 0);
        k2_out<<<512, 512, 100864, stream>>>(Hws, wts, U, offs,
            b2[0], b2[1], b2[2], (float*)d_out, 0);
        // phase expert (mode 1): worst-case 514 tiles (device early-exit)
        k1_hidden<<<514, 512, 135168, stream>>>(obs, wts, U, offs,
            b1[0], b1[1], b1[2], Hws, 1);
        k2_out<<<514, 512, 100864, stream>>>(Hws, wts, U, offs,
            b2[0], b2[1], b2[2], (float*)d_out, 1);
    } else {
        fill_perm<<<256, 256, 0, stream>>>(obs, offs, pb, pc);
        hipFuncSetAttribute((const void*)fused_mlp,
                            hipFuncAttributeMaxDynamicSharedMemorySize, 154112);
        fused_mlp<<<1025, 512, 154112, stream>>>(obs, wts, pb, pc, offs,
            b1[0], b2[0], b1[1], b2[1], b1[2], b2[2], (float*)d_out);
    }
}

// Round 12
// 445.376 us; speedup vs baseline: 1.5351x; 1.0106x over previous
//
#include <hip/hip_runtime.h>
#include <hip/hip_bf16.h>

#define DIN 256
#define DH  1024
#define DF  512
#define NROWS 65536

// workspace layout (bytes)
#define WS_WTS   0
#define WS_PB    4718592
#define WS_PC    4980736
#define WS_CNT   5242880
#define WS_OFFS  5243904

typedef __attribute__((ext_vector_type(8))) short bf16x8;
typedef __attribute__((ext_vector_type(4))) float f32x4;
typedef __attribute__((ext_vector_type(16))) float f32x16;

__device__ __forceinline__ unsigned short f2b(float f) {
    union { float f; unsigned u; } v; v.f = f;
    unsigned r = v.u + 0x7FFFu + ((v.u >> 16) & 1u);
    return (unsigned short)(r >> 16);
}

__device__ __forceinline__ void gll16(const void* g, void* l) {
    __builtin_amdgcn_global_load_lds(
        (const __attribute__((address_space(1))) void*)g,
        (__attribute__((address_space(3))) void*)l, 16, 0, 0);
}

// dst[n][k] = (bf16) src[k][n] ; src is K x N row-major fp32
__global__ __launch_bounds__(256) void transpose_to_bf16(
        const float* __restrict__ src, unsigned short* __restrict__ dst,
        int K, int N) {
    __shared__ float tile[64][65];
    int k0 = blockIdx.x * 64, n0 = blockIdx.y * 64;
    int t = threadIdx.x;
    for (int i = 0; i < 16; ++i) {
        int idx = t + i * 256;
        int kk = idx >> 6, nn = idx & 63;
        tile[kk][nn] = src[(size_t)(k0 + kk) * N + (n0 + nn)];
    }
    __syncthreads();
    for (int i = 0; i < 16; ++i) {
        int idx = t + i * 256;
        int nn = idx >> 6, kk = idx & 63;
        dst[(size_t)(n0 + nn) * K + (k0 + kk)] = f2b(tile[kk][nn]);
    }
}

__device__ __forceinline__ int row_tag(const float* obs, int row) {
    float c2 = obs[(size_t)row * DIN + 2];
    float c3 = obs[(size_t)row * DIN + 3];
    return (c2 == 1.0f && c3 == 0.0f) ? 1 : 0;
}

__global__ __launch_bounds__(256) void tag_count(const float* __restrict__ obs,
                                                 int* __restrict__ cnt) {
    int t = threadIdx.x;
    int tag = row_tag(obs, blockIdx.x * 256 + t);
    unsigned long long m = __ballot(tag);
    __shared__ int wc[4];
    if ((t & 63) == 0) wc[t >> 6] = __popcll(m);
    __syncthreads();
    if (t == 0) cnt[blockIdx.x] = wc[0] + wc[1] + wc[2] + wc[3];
}

__global__ __launch_bounds__(256) void scan256(const int* __restrict__ cnt,
                                               int* __restrict__ offs) {
    __shared__ int s[256];
    int t = threadIdx.x;
    s[t] = cnt[t];
    __syncthreads();
    for (int d = 1; d < 256; d <<= 1) {
        int v = (t >= d) ? s[t - d] : 0;
        __syncthreads();
        s[t] += v;
        __syncthreads();
    }
    offs[t] = s[t] - cnt[t];
    if (t == 255) offs[256] = s[255];
}

__global__ __launch_bounds__(256) void fill_perm(const float* __restrict__ obs,
                                                 const int* __restrict__ offs,
                                                 int* __restrict__ pb,
                                                 int* __restrict__ pc) {
    int t = threadIdx.x, bid = blockIdx.x;
    int row = bid * 256 + t;
    int tag = row_tag(obs, row);
    unsigned long long m = __ballot(tag);
    __shared__ int wc[4];
    int lane = t & 63, wv = t >> 6;
    if (lane == 0) wc[wv] = __popcll(m);
    __syncthreads();
    int woff = 0;
    for (int i = 0; i < 4; ++i) if (i < wv) woff += wc[i];
    int lb = woff + __popcll(m & ((1ull << lane) - 1ull));
    int base_b = offs[bid];
    if (tag) pb[base_b + lb] = row;
    else     pc[bid * 256 - base_b + (t - lb)] = row;
}

// LDS map (dynamic, 154112 B, 1 block/CU). ALL barriers are __syncthreads
// (full drains — the proven-clean R6 mechanism, 376 us). R12 delta vs R6:
// GEMM2 uses mfma_f32_32x32x16_bf16 (2x FLOP per LDS byte): per-wave tile
// 64x128 as 2x4 32x32 fragments; acc = 8 x f32x16 = 128 regs (same budget);
// B-frags reused across 2 row-tiles, hA across 4 quarters -> GEMM2 LDS reads
// 72 -> 24 per chunk per wave. Staging/sync structure byte-identical to R6.
//   ldsX   @ 0      [128][256] bf16 = 64K  persistent, swz (r&7)<<4
//   ldsW1  @ 65536  [64][256]  bf16 = 32K  single-buffered W1 chunk
//   ldsQA  @ 98304  [128][64]  bf16 = 16K  W2 quarter ping
//   ldsQB  @ 114688 [128][64]  bf16 = 16K  W2 quarter pong
//   ldsH   @ 131072 [128][64]  bf16 = 16K
//   ldsB1  @ 147456 float[1024]
//   ldsB2  @ 151552 float[512]
//   ldsPr  @ 153600 int[128]
__global__ __launch_bounds__(512, 2) void fused_mlp(
    const float* __restrict__ obs,
    const unsigned short* __restrict__ wts,
    const int* __restrict__ perm_b, const int* __restrict__ perm_c,
    const int* __restrict__ offs,
    const float* __restrict__ b1_0, const float* __restrict__ b2_0,
    const float* __restrict__ b1_1, const float* __restrict__ b2_1,
    const float* __restrict__ b1_2, const float* __restrict__ b2_2,
    float* __restrict__ out)
{
    extern __shared__ char lds[];
    char* ldsX  = lds;
    char* ldsW1 = lds + 65536;
    char* ldsQA = lds + 98304;
    char* ldsQB = lds + 114688;
    char* ldsH  = lds + 131072;
    float* ldsB1 = (float*)(lds + 147456);
    float* ldsB2 = (float*)(lds + 151552);
    int*  ldsPr  = (int*)(lds + 153600);

    // bijective XCD swizzle: contiguous bid range per XCD
    const int ob = blockIdx.x;
    const int xcd = ob & 7, ii = ob >> 3;
    const int bid = (xcd == 0) ? ii : (129 + (xcd - 1) * 128 + ii);

    int branch, base, cnt;
    const int* perm;
    if (bid < 512) {
        branch = 2; base = bid * 128; cnt = NROWS; perm = nullptr;
    } else {
        int eb = bid - 512;
        int nb = offs[256];
        int nbb = (nb + 127) >> 7;
        int nc = NROWS - nb;
        int ncb = (nc + 127) >> 7;
        if (eb < nbb)            { branch = 0; base = eb * 128;         cnt = nb; perm = perm_b; }
        else if (eb < nbb + ncb) { branch = 1; base = (eb - nbb) * 128; cnt = nc; perm = perm_c; }
        else return;
    }

    const float* b1 = branch == 0 ? b1_0 : (branch == 1 ? b1_1 : b1_2);
    const float* b2 = branch == 0 ? b2_0 : (branch == 1 ? b2_1 : b2_2);
    const char* w1t = (const char*)(wts + (size_t)branch * (DH * DIN));
    const char* w2t = (const char*)(wts + (size_t)3 * DH * DIN + (size_t)branch * (DF * DH));

    const int t = threadIdx.x;
    const int lane = t & 63;
    const int w = t >> 6;
    const int l15 = lane & 15;
    const int g = lane >> 4;
    const int l31 = lane & 31;       // 32x32 fragment lane row/col
    const int kh  = lane >> 5;       // 32x32 fragment k-half

    // ---- prologue: tables + X staging
    ldsB1[t] = b1[t];
    ldsB1[t + 512] = b1[t + 512];
    ldsB2[t] = b2[t];
    if (t < 128) {
        int gr = base + t;
        ldsPr[t] = (gr < cnt) ? (perm ? perm[gr] : gr) : -1;
    }
    #pragma unroll
    for (int i = 0; i < 16; ++i) {
        int idx = t + i * 512;
        int r = idx >> 6, c4 = idx & 63;
        int gr = base + r;
        int grow = gr < cnt ? gr : cnt - 1;
        if (perm) grow = perm[grow];
        f32x4 v = *(const f32x4*)(obs + (size_t)grow * DIN + c4 * 4);
        ushort4 p4;
        p4.x = f2b(v.x); p4.y = f2b(v.y); p4.z = f2b(v.z); p4.w = f2b(v.w);
        *(ushort4*)(ldsX + r * 512 + ((c4 * 8) ^ ((r & 7) << 4))) = p4;
    }
    // stage W1[0] (only exposed stage; once per block)
    #pragma unroll
    for (int i = 0; i < 4; ++i) {
        int slot = t + i * 512;
        int nl = slot >> 5, boff = (slot & 31) << 4;
        gll16(w1t + (size_t)nl * 512 + (boff ^ ((nl & 7) << 4)), ldsW1 + slot * 16);
    }
    __syncthreads();

    // wave roles
    const int rg = w & 3, cg = w >> 2;   // GEMM1: rows rg*32, hcols cg*32 (16x16)
    const int wr = w >> 2, wc = w & 3;   // GEMM2: rows wr*64, col-tile wc*32 per quarter (32x32)

    const int ar0 = rg * 32 + l15, ar1 = ar0 + 16;
    const int asw0 = (ar0 & 7) << 4, asw1 = (ar1 & 7) << 4;
    const int bn0 = cg * 32 + l15, bn1 = bn0 + 16;
    const int bsw0 = (bn0 & 7) << 4, bsw1 = (bn1 & 7) << 4;

    // GEMM2 accumulators: [row-tile][quarter] of 32x32 fragments (8 x f32x16 = 128)
    f32x16 acc32[2][4];
    #pragma unroll
    for (int a = 0; a < 2; ++a)
        #pragma unroll
        for (int b = 0; b < 4; ++b)
            #pragma unroll
            for (int e = 0; e < 16; ++e) acc32[a][b][e] = 0.0f;

    // W2 quarter stage helper: quarter q of chunk hc -> buf (2 gll16/thread)
    #define STAGE_Q(buf, q, hc_)                                               \
        {                                                                      \
            _Pragma("unroll")                                                  \
            for (int i = 0; i < 2; ++i) {                                      \
                int slot = t + i * 512;                                        \
                int nl = slot >> 3, boff = (slot & 7) << 4;                    \
                gll16(w2t + (size_t)((q) * 128 + nl) * 2048 + (hc_) * 128      \
                          + (boff ^ ((nl & 7) << 4)),                          \
                      (buf) + slot * 16);                                      \
            }                                                                  \
        }

    // GEMM2 quarter in 32x32x16: 4 k-steps x 2 row-tiles, B-frag reused x2
    #define QUARTER_MFMA32(buf, q)                                             \
        {                                                                      \
            _Pragma("unroll")                                                  \
            for (int ts = 0; ts < 4; ++ts) {                                   \
                int fr = wc * 32 + l31;                                        \
                bf16x8 bb = *(const bf16x8*)((buf) + fr * 128 +                \
                             ((ts * 32 + kh * 16) ^ ((fr & 7) << 4)));         \
                acc32[0][q] = __builtin_amdgcn_mfma_f32_32x32x16_bf16(         \
                    hA32[0][ts], bb, acc32[0][q], 0, 0, 0);                    \
                acc32[1][q] = __builtin_amdgcn_mfma_f32_32x32x16_bf16(         \
                    hA32[1][ts], bb, acc32[1][q], 0, 0, 0);                    \
            }                                                                  \
        }

    for (int hc = 0; hc < 16; ++hc) {
        // ---- I1: stage q0->QA ; GEMM1 (16x16, unchanged) + bias/relu -> H
        STAGE_Q(ldsQA, 0, hc);
        f32x4 aH[2][2];
        #pragma unroll
        for (int a = 0; a < 2; ++a)
            #pragma unroll
            for (int b = 0; b < 2; ++b)
                #pragma unroll
                for (int e = 0; e < 4; ++e) aH[a][b][e] = 0.0f;
        __builtin_amdgcn_s_setprio(1);
        #pragma unroll
        for (int kk = 0; kk < 8; ++kk) {
            int kb = kk * 64 + g * 16;
            bf16x8 a0 = *(const bf16x8*)(ldsX  + ar0 * 512 + (kb ^ asw0));
            bf16x8 a1 = *(const bf16x8*)(ldsX  + ar1 * 512 + (kb ^ asw1));
            bf16x8 b0 = *(const bf16x8*)(ldsW1 + bn0 * 512 + (kb ^ bsw0));
            bf16x8 b1f = *(const bf16x8*)(ldsW1 + bn1 * 512 + (kb ^ bsw1));
            aH[0][0] = __builtin_amdgcn_mfma_f32_16x16x32_bf16(a0, b0,  aH[0][0], 0, 0, 0);
            aH[0][1] = __builtin_amdgcn_mfma_f32_16x16x32_bf16(a0, b1f, aH[0][1], 0, 0, 0);
            aH[1][0] = __builtin_amdgcn_mfma_f32_16x16x32_bf16(a1, b0,  aH[1][0], 0, 0, 0);
            aH[1][1] = __builtin_amdgcn_mfma_f32_16x16x32_bf16(a1, b1f, aH[1][1], 0, 0, 0);
        }
        __builtin_amdgcn_s_setprio(0);
        {
            float b1v0 = ldsB1[hc * 64 + cg * 32 + l15];
            float b1v1 = ldsB1[hc * 64 + cg * 32 + 16 + l15];
            #pragma unroll
            for (int art = 0; art < 2; ++art)
                #pragma unroll
                for (int bct = 0; bct < 2; ++bct) {
                    int col2 = (cg * 32 + bct * 16 + l15) * 2;
                    float bv = bct ? b1v1 : b1v0;
                    #pragma unroll
                    for (int r = 0; r < 4; ++r) {
                        int hrow = rg * 32 + art * 16 + g * 4 + r;
                        float vv = fmaxf(aH[art][bct][r] + bv, 0.0f);
                        *(unsigned short*)(ldsH + hrow * 128 + (col2 ^ ((hrow & 7) << 4))) = f2b(vv);
                    }
                }
        }
        __syncthreads();   // B1: drains q0; H visible

        // ---- I2: stage q1->QB ; hA32 loads (reused all 4 quarters) ; GEMM2 q0 (QA)
        STAGE_Q(ldsQB, 1, hc);
        bf16x8 hA32[2][4];
        #pragma unroll
        for (int rt = 0; rt < 2; ++rt) {
            int hr = wr * 64 + rt * 32 + l31;
            #pragma unroll
            for (int ts = 0; ts < 4; ++ts)
                hA32[rt][ts] = *(const bf16x8*)(ldsH + hr * 128 +
                               ((ts * 32 + kh * 16) ^ ((hr & 7) << 4)));
        }
        __builtin_amdgcn_s_setprio(1);
        QUARTER_MFMA32(ldsQA, 0);
        __builtin_amdgcn_s_setprio(0);
        __syncthreads();   // B2: drains q1

        // ---- I3: stage q2->QA ; GEMM2 q1 (QB)
        STAGE_Q(ldsQA, 2, hc);
        __builtin_amdgcn_s_setprio(1);
        QUARTER_MFMA32(ldsQB, 1);
        __builtin_amdgcn_s_setprio(0);
        __syncthreads();   // B3: drains q2

        // ---- I4: stage q3->QB ; GEMM2 q2 (QA)
        STAGE_Q(ldsQB, 3, hc);
        __builtin_amdgcn_s_setprio(1);
        QUARTER_MFMA32(ldsQA, 2);
        __builtin_amdgcn_s_setprio(0);
        __syncthreads();   // B4: drains q3

        // ---- I5: stage W1[hc+1] ; GEMM2 q3 (QB)
        if (hc < 15) {
            int nchunk = hc + 1;
            #pragma unroll
            for (int i = 0; i < 4; ++i) {
                int slot = t + i * 512;
                int nl = slot >> 5, boff = (slot & 31) << 4;
                gll16(w1t + (size_t)(nchunk * 64 + nl) * 512 + (boff ^ ((nl & 7) << 4)),
                      ldsW1 + slot * 16);
            }
        }
        __builtin_amdgcn_s_setprio(1);
        QUARTER_MFMA32(ldsQB, 3);
        __builtin_amdgcn_s_setprio(0);
        __syncthreads();   // B5: drains W1[hc+1]
    }

    // ---- epilogue: bias2 + permuted scatter store (32x32 C/D layout:
    // col = lane&31, row = (reg&3) + 8*(reg>>2) + 4*(lane>>5))
    float b2v[4];
    #pragma unroll
    for (int q = 0; q < 4; ++q)
        b2v[q] = ldsB2[q * 128 + wc * 32 + l31];
    const int cb = (branch == 2) ? DF : 0;
    #pragma unroll
    for (int rt = 0; rt < 2; ++rt)
        #pragma unroll
        for (int reg = 0; reg < 16; ++reg) {
            int row = wr * 64 + rt * 32 + (reg & 3) + 8 * (reg >> 2) + 4 * kh;
            int prow = ldsPr[row];
            if (prow >= 0) {
                float* op = out + (size_t)prow * (2 * DF) + cb;
                #pragma unroll
                for (int q = 0; q < 4; ++q)
                    op[q * 128 + wc * 32 + l31] = acc32[rt][q][reg] + b2v[q];
            }
        }
}

extern "C" void kernel_launch(void* const* d_in, const int* in_sizes, int n_in,
                              void* d_out, int out_size, void* d_ws, size_t ws_size,
                              hipStream_t stream) {
    const float* obs = (const float*)d_in[0];
    const float* W1[3] = {(const float*)d_in[1], (const float*)d_in[5], (const float*)d_in[9]};
    const float* b1[3] = {(const float*)d_in[2], (const float*)d_in[6], (const float*)d_in[10]};
    const float* W2[3] = {(const float*)d_in[3], (const float*)d_in[7], (const float*)d_in[11]};
    const float* b2[3] = {(const float*)d_in[4], (const float*)d_in[8], (const float*)d_in[12]};

    char* ws = (char*)d_ws;
    unsigned short* wts = (unsigned short*)(ws + WS_WTS);
    int* pb   = (int*)(ws + WS_PB);
    int* pc   = (int*)(ws + WS_PC);
    int* cnt  = (int*)(ws + WS_CNT);
    int* offs = (int*)(ws + WS_OFFS);

    for (int br = 0; br < 3; ++br) {
        transpose_to_bf16<<<dim3(DIN / 64, DH / 64), 256, 0, stream>>>(
            W1[br], wts + (size_t)br * DH * DIN, DIN, DH);
        transpose_to_bf16<<<dim3(DH / 64, DF / 64), 256, 0, stream>>>(
            W2[br], wts + (size_t)3 * DH * DIN + (size_t)br * DF * DH, DH, DF);
    }
    tag_count<<<256, 256, 0, stream>>>(obs, cnt);
    scan256<<<1, 256, 0, stream>>>(cnt, offs);
    fill_perm<<<256, 256, 0, stream>>>(obs, offs, pb, pc);

    hipFuncSetAttribute((const void*)fused_mlp,
                        hipFuncAttributeMaxDynamicSharedMemorySize, 154112);
    fused_mlp<<<1025, 512, 154112, stream>>>(obs, wts, pb, pc, offs,
        b1[0], b2[0], b1[1], b2[1], b1[2], b2[2], (float*)d_out);
}